// Round 1
// baseline (565.162 us; speedup 1.0000x reference)
//
#include <hip/hip_runtime.h>
#include <hip/hip_bf16.h>
#include <stdint.h>

// Problem: out[b,s,o] = sum_d FWHT(x)[b,s,d]/sqrt(n) * W[o,d] + bias[o]
// Folded:  out = x @ W'^T + bias,  W' = FWHT(W rows)/sqrt(n)  (H symmetric)
// Shapes: x (4,2048,8192) f32 -> M=8192,K=8192 ; W (2048,8192) -> N=2048 ; out f32.

#define M_TOTAL 8192
#define K_TOTAL 8192
#define N_TOTAL 2048
#define D_IN 8192

typedef __attribute__((ext_vector_type(8))) short short8;
typedef __attribute__((ext_vector_type(4))) float f32x4;

typedef __attribute__((address_space(1))) void void_g;
typedef __attribute__((address_space(3))) void void_l;

__device__ __forceinline__ short f2bf(float f) {
  __hip_bfloat16 h = __float2bfloat16(f);
  return *reinterpret_cast<short*>(&h);
}

// ---------------- kernel 1: x fp32 -> bf16 ----------------
__global__ void cvt_x_kernel(const float* __restrict__ x, short* __restrict__ xb, long n) {
  long stride = (long)gridDim.x * blockDim.x * 8;
  for (long i = ((long)blockIdx.x * blockDim.x + threadIdx.x) * 8; i < n; i += stride) {
    float4 v0 = *(const float4*)(x + i);
    float4 v1 = *(const float4*)(x + i + 4);
    short8 o;
    o[0] = f2bf(v0.x); o[1] = f2bf(v0.y); o[2] = f2bf(v0.z); o[3] = f2bf(v0.w);
    o[4] = f2bf(v1.x); o[5] = f2bf(v1.y); o[6] = f2bf(v1.z); o[7] = f2bf(v1.w);
    *(short8*)(xb + i) = o;
  }
}

// ---------------- kernel 2: W' = FWHT(W rows) / sqrt(n), bf16 ----------------
__global__ void fwht_w_kernel(const float* __restrict__ W, short* __restrict__ Wh) {
  __shared__ float buf[D_IN];
  const int row = blockIdx.x;
  const float* src = W + (long)row * D_IN;
  for (int i = threadIdx.x; i < D_IN / 4; i += blockDim.x)
    ((float4*)buf)[i] = ((const float4*)src)[i];
  for (int h = 1; h < D_IN; h <<= 1) {
    __syncthreads();
    for (int p = threadIdx.x; p < D_IN / 2; p += blockDim.x) {
      int i = ((p & ~(h - 1)) << 1) | (p & (h - 1));
      float a = buf[i], b = buf[i + h];
      buf[i] = a + b;
      buf[i + h] = a - b;
    }
  }
  __syncthreads();
  const float s = 0.011048543456039806f; // 1/sqrt(8192)
  short* dst = Wh + (long)row * D_IN;
  for (int i = threadIdx.x; i < D_IN; i += blockDim.x)
    dst[i] = f2bf(buf[i] * s);
}

// ---------------- kernel 3: bf16 GEMM, C = A @ B^T + bias ----------------
// A [M][K] bf16 row-major, B [N][K] bf16 row-major (W'), C [M][N] f32.
#define BM 128
#define BN 128
#define BK 64

__global__ __launch_bounds__(256) void gemm_kernel(const short* __restrict__ A,
                                                   const short* __restrict__ B,
                                                   const float* __restrict__ bias,
                                                   float* __restrict__ C) {
  __shared__ short sA[BM][BK];
  __shared__ short sB[BN][BK];

  // XCD-aware bijective swizzle (nwg = 1024, divisible by 8)
  int bid = blockIdx.x;
  int swz = (bid & 7) * (gridDim.x >> 3) + (bid >> 3);
  int bm = swz >> 4;       // N_TOTAL/BN = 16 tiles in N, bn fastest
  int bn = swz & 15;

  const int tid = threadIdx.x;
  const int l = tid & 63;
  const int w = tid >> 6;          // 4 waves: 2x2
  const int wr = w >> 1, wc = w & 1;

  const long tileM = (long)bm * BM;
  const long tileN = (long)bn * BN;

  f32x4 acc[4][4];
#pragma unroll
  for (int m = 0; m < 4; ++m)
#pragma unroll
    for (int n = 0; n < 4; ++n)
      acc[m][n] = (f32x4){0.f, 0.f, 0.f, 0.f};

  const int lr = l & 15;        // fragment row within 16
  const int lkb = (l >> 4) * 8; // fragment k element offset

  for (int k0 = 0; k0 < K_TOTAL; k0 += BK) {
    __syncthreads(); // previous iteration's LDS reads done
#pragma unroll
    for (int q = 0; q < 4; ++q) {
      int e = (q * 256 + tid) * 8; // bf16 element index within 128x64 tile
      int row = e >> 6, col = e & 63;
      __builtin_amdgcn_global_load_lds((void_g*)(A + (tileM + row) * (long)K_TOTAL + k0 + col),
                                       (void_l*)(&sA[0][0] + e), 16, 0, 0);
      __builtin_amdgcn_global_load_lds((void_g*)(B + (tileN + row) * (long)K_TOTAL + k0 + col),
                                       (void_l*)(&sB[0][0] + e), 16, 0, 0);
    }
    __syncthreads(); // staging visible (compiler drains vmcnt before barrier)

#pragma unroll
    for (int ks = 0; ks < 2; ++ks) {
      short8 a[4], b[4];
#pragma unroll
      for (int m = 0; m < 4; ++m)
        a[m] = *(const short8*)&sA[wr * 64 + m * 16 + lr][lkb + ks * 32];
#pragma unroll
      for (int n = 0; n < 4; ++n)
        b[n] = *(const short8*)&sB[wc * 64 + n * 16 + lr][lkb + ks * 32];
#pragma unroll
      for (int m = 0; m < 4; ++m)
#pragma unroll
        for (int n = 0; n < 4; ++n)
          acc[m][n] = __builtin_amdgcn_mfma_f32_16x16x32_bf16(a[m], b[n], acc[m][n], 0, 0, 0);
    }
  }

  // epilogue: C[row][col] = acc + bias[col]
  const int rbase = (int)tileM + wr * 64 + (l >> 4) * 4;
  const int cbase = (int)tileN + wc * 64 + lr;
#pragma unroll
  for (int n = 0; n < 4; ++n) {
    float bv = bias[cbase + n * 16];
#pragma unroll
    for (int m = 0; m < 4; ++m)
#pragma unroll
      for (int r = 0; r < 4; ++r)
        C[(long)(rbase + m * 16 + r) * N_TOTAL + cbase + n * 16] = acc[m][n][r] + bv;
  }
}

extern "C" void kernel_launch(void* const* d_in, const int* in_sizes, int n_in,
                              void* d_out, int out_size, void* d_ws, size_t ws_size,
                              hipStream_t stream) {
  const float* x = (const float*)d_in[0];
  const float* W = (const float*)d_in[1];
  const float* bias = (const float*)d_in[2];
  float* out = (float*)d_out;

  short* xb = (short*)d_ws;                                          // 8192*8192*2 = 134 MB
  short* wh = (short*)((char*)d_ws + (size_t)M_TOTAL * K_TOTAL * 2); // 2048*8192*2 = 33.5 MB

  cvt_x_kernel<<<2048, 256, 0, stream>>>(x, xb, (long)M_TOTAL * K_TOTAL);
  fwht_w_kernel<<<N_TOTAL, 256, 0, stream>>>(W, wh);

  int grid = (M_TOTAL / BM) * (N_TOTAL / BN); // 64 * 16 = 1024
  gemm_kernel<<<grid, 256, 0, stream>>>(xb, wh, bias, out);
}

// Round 2
// 473.048 us; speedup vs baseline: 1.1947x; 1.1947x over previous
//
#include <hip/hip_runtime.h>
#include <hip/hip_bf16.h>
#include <stdint.h>

// out = x @ W'^T + bias, W' = FWHT(W rows)/sqrt(n)  (H symmetric, folded into W)
// x (4,2048,8192) f32 -> M=8192, K=8192 ; W (2048,8192) -> N=2048 ; out f32.

#define M_TOTAL 8192
#define K_TOTAL 8192
#define N_TOTAL 2048
#define D_IN 8192

typedef __attribute__((ext_vector_type(8))) short short8;
typedef __attribute__((ext_vector_type(4))) float f32x4;

typedef __attribute__((address_space(1))) void void_g;
typedef __attribute__((address_space(3))) void void_l;

__device__ __forceinline__ short f2bf(float f) {
  __hip_bfloat16 h = __float2bfloat16(f);
  return *reinterpret_cast<short*>(&h);
}

// ---------------- kernel 1: x fp32 -> bf16 ----------------
__global__ void cvt_x_kernel(const float* __restrict__ x, short* __restrict__ xb, long n) {
  long stride = (long)gridDim.x * blockDim.x * 8;
  for (long i = ((long)blockIdx.x * blockDim.x + threadIdx.x) * 8; i < n; i += stride) {
    float4 v0 = *(const float4*)(x + i);
    float4 v1 = *(const float4*)(x + i + 4);
    short8 o;
    o[0] = f2bf(v0.x); o[1] = f2bf(v0.y); o[2] = f2bf(v0.z); o[3] = f2bf(v0.w);
    o[4] = f2bf(v1.x); o[5] = f2bf(v1.y); o[6] = f2bf(v1.z); o[7] = f2bf(v1.w);
    *(short8*)(xb + i) = o;
  }
}

// ---------------- kernel 2: W' = FWHT(W rows) / sqrt(n), bf16 ----------------
__global__ void fwht_w_kernel(const float* __restrict__ W, short* __restrict__ Wh) {
  __shared__ float buf[D_IN];
  const int row = blockIdx.x;
  const float* src = W + (long)row * D_IN;
  for (int i = threadIdx.x; i < D_IN / 4; i += blockDim.x)
    ((float4*)buf)[i] = ((const float4*)src)[i];
  for (int h = 1; h < D_IN; h <<= 1) {
    __syncthreads();
    for (int p = threadIdx.x; p < D_IN / 2; p += blockDim.x) {
      int i = ((p & ~(h - 1)) << 1) | (p & (h - 1));
      float a = buf[i], b = buf[i + h];
      buf[i] = a + b;
      buf[i + h] = a - b;
    }
  }
  __syncthreads();
  const float s = 0.011048543456039806f; // 1/sqrt(8192)
  short* dst = Wh + (long)row * D_IN;
  for (int i = threadIdx.x; i < D_IN; i += blockDim.x)
    dst[i] = f2bf(buf[i] * s);
}

// ---------------- kernel 3: 256x256 multi-phase bf16 GEMM, C = A @ B^T + bias ----
// A [M][K] bf16, B [N][K] bf16 (W'), C [M][N] f32.
// 512 threads = 8 waves (2M x 4N). BK=64, K-tile double buffer.
// LDS slots: per (buf, kshalf): 256 rows x 32 cols bf16 = 16 KiB, stored
// chunk-major [kb4][row][8] (kb4 = 16B column chunk) -> conflict-free b128 reads.
#define BM 256
#define BN 256
#define BK 64
#define NKT (K_TOTAL / BK)

#define ASLOT(B, KS) ((((B) << 1) | (KS)) << 13)
#define BSLOT(B, KS) (32768 + ((((B) << 1) | (KS)) << 13))

// stage one slot: 2 x global_load_lds(16B) per thread; SRCROW already includes
// per-thread row*K and (tid>>8)*8 column shorts; KCOL = k0 + ks*32
#define STAGE(SLOTBASE, SRCROW, KCOL)                                                             \
  __builtin_amdgcn_global_load_lds((void_g*)((SRCROW) + (KCOL)),                                  \
                                   (void_l*)&lds[(SLOTBASE) + sdst], 16, 0, 0);                   \
  __builtin_amdgcn_global_load_lds((void_g*)((SRCROW) + (KCOL) + 16),                             \
                                   (void_l*)&lds[(SLOTBASE) + sdst + 4096], 16, 0, 0);

#define LDA4(SLOT, MH)                                                                            \
  _Pragma("unroll") for (int m = 0; m < 4; ++m)                                                   \
      a[m] = *(const short8*)&lds[(SLOT) + aoff + ((MH) * 64 + m * 16) * 8];

#define LDB4(SLOT)                                                                                \
  _Pragma("unroll") for (int n = 0; n < 4; ++n)                                                   \
      bfr[n] = *(const short8*)&lds[(SLOT) + boff + n * 128];

#define MFMA_BLOCK(MH)                                                                            \
  __builtin_amdgcn_s_setprio(1);                                                                  \
  _Pragma("unroll") for (int m = 0; m < 4; ++m) {                                                 \
    _Pragma("unroll") for (int n = 0; n < 4; ++n)                                                 \
        acc[MH][m][n] =                                                                           \
            __builtin_amdgcn_mfma_f32_16x16x32_bf16(a[m], bfr[n], acc[MH][m][n], 0, 0, 0);        \
  }                                                                                               \
  __builtin_amdgcn_s_setprio(0);

__global__ __launch_bounds__(512, 2) void gemm_kernel(const short* __restrict__ A,
                                                      const short* __restrict__ B,
                                                      const float* __restrict__ bias,
                                                      float* __restrict__ C) {
  __shared__ __attribute__((aligned(16))) short lds[65536]; // 128 KiB

  const int tid = threadIdx.x;
  const int l = tid & 63;
  const int w = tid >> 6;  // 8 waves
  const int wm = w >> 2;   // 0..1 (M half)
  const int wn = w & 3;    // 0..3 (N quarter)
  const int lr = l & 15;
  const int lq = l >> 4;   // 0..3 (16B k-chunk)

  // XCD-aware bijective swizzle (nwg = 256, 256 % 8 == 0)
  const int bid = blockIdx.x;
  const int swz = (bid & 7) * 32 + (bid >> 3);
  const int bm = swz >> 3; // 0..31
  const int bn = swz & 7;  // 0..7
  const long tileM = (long)bm * BM;
  const long tileN = (long)bn * BN;

  // staging constants: thread -> (row = tid&255, kb4 base = tid>>8)
  const int sdst = tid * 8; // shorts within slot (+ q*4096)
  const short* aS = A + (tileM + (tid & 255)) * (long)K_TOTAL + (tid >> 8) * 8;
  const short* bS = B + (tileN + (tid & 255)) * (long)K_TOTAL + (tid >> 8) * 8;

  // frag-read constants (short offsets within a slot)
  const int aoff = lq * 2048 + (wm * 128 + lr) * 8;
  const int boff = lq * 2048 + (wn * 64 + lr) * 8;

  f32x4 acc[2][4][4];
#pragma unroll
  for (int mh = 0; mh < 2; ++mh)
#pragma unroll
    for (int m = 0; m < 4; ++m)
#pragma unroll
      for (int n = 0; n < 4; ++n)
        acc[mh][m][n] = (f32x4){0.f, 0.f, 0.f, 0.f};

  // prologue: stage K-tile 0 into buf 0 (order: Aks0, Bks0, Aks1, Bks1)
  STAGE(ASLOT(0, 0), aS, 0);
  STAGE(BSLOT(0, 0), bS, 0);
  STAGE(ASLOT(0, 1), aS, 32);
  STAGE(BSLOT(0, 1), bS, 32);
  // wait oldest 4 (ks0 slots), then rendezvous -> cross-wave data visible
  asm volatile("s_waitcnt vmcnt(4)\ns_barrier" ::: "memory");

  short8 a[4], bfr[4];

  for (int t = 0; t < NKT; ++t) {
    const int bsel = t & 1;
    const int nb = bsel ^ 1;
    const int kn = (t + 1) * BK;
    const bool pf = (t + 1) < NKT;
    const int sA0 = ASLOT(bsel, 0), sA1 = ASLOT(bsel, 1);
    const int sB0 = BSLOT(bsel, 0), sB1 = BSLOT(bsel, 1);

    // ---- phase 0: ks0, mh0 ----
    LDB4(sB0);
    LDA4(sA0, 0);
    if (pf) { STAGE(ASLOT(nb, 0), aS, kn); }
    __builtin_amdgcn_s_barrier();
    MFMA_BLOCK(0);
    __builtin_amdgcn_s_barrier();

    // ---- phase 1: ks0, mh1 ----
    LDA4(sA0, 1);
    if (pf) { STAGE(BSLOT(nb, 0), bS, kn); }
    __builtin_amdgcn_s_barrier();
    MFMA_BLOCK(1);
    // guard ks1 slots of current buf (staged 4 phases ago): wait-then-barrier
    if (pf) asm volatile("s_waitcnt vmcnt(4)\ns_barrier" ::: "memory");
    else    asm volatile("s_waitcnt vmcnt(0)\ns_barrier" ::: "memory");

    // ---- phase 2: ks1, mh0 ----
    LDB4(sB1);
    LDA4(sA1, 0);
    if (pf) { STAGE(ASLOT(nb, 1), aS, kn + 32); }
    __builtin_amdgcn_s_barrier();
    MFMA_BLOCK(0);
    __builtin_amdgcn_s_barrier();

    // ---- phase 3: ks1, mh1 ----
    LDA4(sA1, 1);
    if (pf) { STAGE(BSLOT(nb, 1), bS, kn + 32); }
    __builtin_amdgcn_s_barrier();
    MFMA_BLOCK(1);
    // guard next iteration's ks0 slots (staged this iter, phases 0-1)
    if (pf) asm volatile("s_waitcnt vmcnt(4)\ns_barrier" ::: "memory");
    else    __builtin_amdgcn_s_barrier();
  }

  // epilogue: C += bias
  const int rb0 = (int)tileM + wm * 128 + lq * 4;
  const int cb0 = (int)tileN + wn * 64 + lr;
#pragma unroll
  for (int mh = 0; mh < 2; ++mh)
#pragma unroll
    for (int n = 0; n < 4; ++n) {
      float bv = bias[cb0 + n * 16];
#pragma unroll
      for (int m = 0; m < 4; ++m) {
        const int r0 = rb0 + mh * 64 + m * 16;
#pragma unroll
        for (int r = 0; r < 4; ++r)
          C[(long)(r0 + r) * N_TOTAL + cb0 + n * 16] = acc[mh][m][n][r] + bv;
      }
    }
}

extern "C" void kernel_launch(void* const* d_in, const int* in_sizes, int n_in,
                              void* d_out, int out_size, void* d_ws, size_t ws_size,
                              hipStream_t stream) {
  const float* x = (const float*)d_in[0];
  const float* W = (const float*)d_in[1];
  const float* bias = (const float*)d_in[2];
  float* out = (float*)d_out;

  short* xb = (short*)d_ws;                                          // 8192*8192*2 = 134 MB
  short* wh = (short*)((char*)d_ws + (size_t)M_TOTAL * K_TOTAL * 2); // 2048*8192*2 = 33.5 MB

  cvt_x_kernel<<<2048, 256, 0, stream>>>(x, xb, (long)M_TOTAL * K_TOTAL);
  fwht_w_kernel<<<N_TOTAL, 256, 0, stream>>>(W, wh);

  const int grid = (M_TOTAL / BM) * (N_TOTAL / BN); // 32 * 8 = 256
  gemm_kernel<<<grid, 512, 0, stream>>>(xb, wh, bias, out);
}